// Round 2
// baseline (599.140 us; speedup 1.0000x reference)
//
#include <hip/hip_runtime.h>
#include <hip/hip_bf16.h>

constexpr int B = 2, C = 64, H = 112, W = 112, N2 = 49;
constexpr int HW = H * W;        // 12544
constexpr int NPIX = B * HW;     // 25088
constexpr float EPS_LN = 1e-6f, EPS_NORM = 1e-7f;

__device__ __forceinline__ float wave_sum(float v) {
    v += __shfl_xor(v, 32);
    v += __shfl_xor(v, 16);
    v += __shfl_xor(v, 8);
    v += __shfl_xor(v, 4);
    v += __shfl_xor(v, 2);
    v += __shfl_xor(v, 1);
    return v;
}

// Kernel 1: transpose semantic/spatial to [p][64] f32, compute px = range_proj(semantic)
__global__ __launch_bounds__(512) void k1_range_proj(
    const float* __restrict__ sem, const float* __restrict__ spat,
    const float* __restrict__ w1, const float* __restrict__ b1,
    const float* __restrict__ g, const float* __restrict__ beta,
    const float* __restrict__ w2, const float* __restrict__ b2,
    float* __restrict__ sem_t, float* __restrict__ spat_t, float* __restrict__ px_t)
{
    __shared__ float w1t[64 * 65], w2t[64 * 65];   // [k][co], pitch 65
    __shared__ float xt[64 * 65];                  // [i][c], pitch 65
    __shared__ float vbuf[8 * 72];                 // per-wave silu vector
    __shared__ float sb1[64], sg[64], sbeta[64], sb2[64];

    const int tid = threadIdx.x;
    const int p0 = blockIdx.x * 64;
    const int b = p0 / HW;
    const int hw0 = p0 - b * HW;

    for (int idx = tid; idx < 4096; idx += 512) {
        int co = idx >> 6, k = idx & 63;
        w1t[k * 65 + co] = w1[idx];
        w2t[k * 65 + co] = w2[idx];
    }
    if (tid < 64) {
        sb1[tid] = b1[tid]; sg[tid] = g[tid];
        sbeta[tid] = beta[tid]; sb2[tid] = b2[tid];
    }
    for (int idx = tid; idx < 4096; idx += 512) {
        int c = idx >> 6, i = idx & 63;
        xt[i * 65 + c] = sem[(size_t)b * C * HW + (size_t)c * HW + hw0 + i];
    }
    __syncthreads();

    for (int idx = tid; idx < 4096; idx += 512) {
        int i = idx >> 6, c = idx & 63;
        sem_t[(size_t)(p0 + i) * 64 + c] = xt[i * 65 + c];
    }

    const int wv = tid >> 6, lane = tid & 63;
    const float rb1 = sb1[lane], rg = sg[lane], rbeta = sbeta[lane], rb2 = sb2[lane];
    for (int ii = 0; ii < 8; ++ii) {
        int i = wv * 8 + ii;
        float acc = rb1;
#pragma unroll
        for (int k = 0; k < 64; ++k) acc += w1t[k * 65 + lane] * xt[i * 65 + k];
        float mean = wave_sum(acc) * (1.f / 64.f);
        float d = acc - mean;
        float var = wave_sum(d * d) * (1.f / 64.f);
        float y = rg * d * rsqrtf(var + EPS_LN) + rbeta;
        float s = y / (1.f + __expf(-y));          // SiLU
        vbuf[wv * 72 + lane] = s;
        float acc2 = rb2;
#pragma unroll
        for (int k = 0; k < 64; ++k) acc2 += w2t[k * 65 + lane] * vbuf[wv * 72 + k];
        px_t[(size_t)(p0 + i) * 64 + lane] = acc2;
    }
    __syncthreads();

    for (int idx = tid; idx < 4096; idx += 512) {
        int c = idx >> 6, i = idx & 63;
        xt[i * 65 + c] = spat[(size_t)b * C * HW + (size_t)c * HW + hw0 + i];
    }
    __syncthreads();
    for (int idx = tid; idx < 4096; idx += 512) {
        int i = idx >> 6, c = idx & 63;
        spat_t[(size_t)(p0 + i) * 64 + c] = xt[i * 65 + c];
    }
}

// Kernel 2: bilateral combined weights + gated fixup + normalize -> comb_g[p][49]
__global__ __launch_bounds__(256) void k2_combined(
    const float* __restrict__ px_t, const float* __restrict__ sem_t,
    const float* __restrict__ fw1, const float* __restrict__ fb1_,
    const float* __restrict__ fg_, const float* __restrict__ fbeta_,
    const float* __restrict__ fw2, const float* __restrict__ fb2_,
    const float* __restrict__ sigma_, float* __restrict__ comb_g)
{
    __shared__ float fw1t[113 * 65];   // [k][o], o padded to 64 (pitch 65)
    __shared__ float fw2t[49 * 65];
    __shared__ float sb1[64], sg[64], sbeta[64], sb2[64];
    __shared__ float inbuf[4][128];    // [0..48] combined, [49..112] semantic
    __shared__ float fbuf[4][64];

    const int tid = threadIdx.x;
    for (int idx = tid; idx < 113 * 64; idx += 256) {
        int o = idx / 113, k = idx - o * 113;
        fw1t[k * 65 + o] = (o < 49) ? fw1[o * 113 + k] : 0.f;
    }
    for (int idx = tid; idx < 49 * 64; idx += 256) {
        int o = idx / 49, k = idx - o * 49;
        fw2t[k * 65 + o] = (o < 49) ? fw2[o * 49 + k] : 0.f;
    }
    if (tid < 64) {
        sb1[tid] = (tid < 49) ? fb1_[tid] : 0.f;
        sg[tid] = (tid < 49) ? fg_[tid] : 0.f;
        sbeta[tid] = (tid < 49) ? fbeta_[tid] : 0.f;
        sb2[tid] = (tid < 49) ? fb2_[tid] : 0.f;
    }
    __syncthreads();

    const float sigma = sigma_[0];
    const float inv2s2 = 1.f / (2.f * sigma * sigma);
    const int wv = tid >> 6, lane = tid & 63;
    const float lb1 = sb1[lane], lg = sg[lane], lbeta = sbeta[lane], lb2 = sb2[lane];

    for (int ii = 0; ii < 8; ++ii) {
        int p = blockIdx.x * 32 + wv * 8 + ii;
        int b = p / HW; int hw = p - b * HW; int h = hw / W; int w = hw - h * W;
        float ctr = px_t[(size_t)p * 64 + lane];
        inbuf[wv][49 + lane] = sem_t[(size_t)p * 64 + lane];
        float combv = 0.f;
#pragma unroll
        for (int n = 0; n < 49; ++n) {
            const int dy = n / 7 - 3, dx = n % 7 - 3;
            const float d2n = (float)(dy * dy + dx * dx);
            int hh = h + dy, ww = w + dx;
            float wgt = 0.f;
            if (hh >= 0 && hh < H && ww >= 0 && ww < W) {   // wave-uniform branch
                int q = p + dy * W + dx;
                float v = px_t[(size_t)q * 64 + lane] - ctr;
                float dist2 = wave_sum(v * v);
                wgt = __expf(-(dist2 * (1.f / 128.f) + d2n * inv2s2));
            }
            if (lane == n) { combv = wgt; inbuf[wv][n] = wgt; }
        }
        // fixup conv1 (49 x 113)
        float f1 = lb1;
#pragma unroll
        for (int k = 0; k < 113; ++k) f1 += fw1t[k * 65 + lane] * inbuf[wv][k];
        // LN over 49 channels
        float fm = (lane < 49) ? f1 : 0.f;
        float mean = wave_sum(fm) * (1.f / 49.f);
        float d = (lane < 49) ? (f1 - mean) : 0.f;
        float var = wave_sum(d * d) * (1.f / 49.f);
        float y = lg * d * rsqrtf(var + EPS_LN) + lbeta;   // 0 for lanes >= 49
        float s = y / (1.f + __expf(-y));
        fbuf[wv][lane] = s;
        float f2 = lb2;
#pragma unroll
        for (int k = 0; k < 49; ++k) f2 += fw2t[k * 65 + lane] * fbuf[wv][k];
        float gate = 1.f + 1.f / (1.f + __expf(-f2));
        combv *= gate;
        float tot = wave_sum(combv);
        combv /= (tot + EPS_NORM);
        if (lane < 49) comb_g[(size_t)p * 49 + lane] = combv;
    }
}

// Kernel 3: weighted neighborhood reduction + output_proj -> out_t[p][64]
__global__ __launch_bounds__(256) void k3_output(
    const float* __restrict__ spat_t, const float* __restrict__ comb_g,
    const float* __restrict__ w1, const float* __restrict__ b1,
    const float* __restrict__ g, const float* __restrict__ beta,
    const float* __restrict__ w2, const float* __restrict__ b2,
    float* __restrict__ out_t)
{
    __shared__ float w1t[64 * 65], w2t[64 * 65];
    __shared__ float sb1[64], sg[64], sbeta[64], sb2[64];
    __shared__ float cbuf[4][52];
    __shared__ float vbuf[4][72];

    const int tid = threadIdx.x;
    for (int idx = tid; idx < 4096; idx += 256) {
        int co = idx >> 6, k = idx & 63;
        w1t[k * 65 + co] = w1[idx];
        w2t[k * 65 + co] = w2[idx];
    }
    if (tid < 64) {
        sb1[tid] = b1[tid]; sg[tid] = g[tid];
        sbeta[tid] = beta[tid]; sb2[tid] = b2[tid];
    }
    __syncthreads();

    const int wv = tid >> 6, lane = tid & 63;
    const float rb1 = sb1[lane], rg = sg[lane], rbeta = sbeta[lane], rb2 = sb2[lane];
    for (int ii = 0; ii < 8; ++ii) {
        int p = blockIdx.x * 32 + wv * 8 + ii;
        int b = p / HW; int hw = p - b * HW; int h = hw / W; int w = hw - h * W;
        if (lane < 49) cbuf[wv][lane] = comb_g[(size_t)p * 49 + lane];
        float acc = 0.f;
#pragma unroll
        for (int n = 0; n < 49; ++n) {
            const int dy = n / 7 - 3, dx = n % 7 - 3;
            int hh = h + dy, ww = w + dx;
            if (hh >= 0 && hh < H && ww >= 0 && ww < W) {
                int q = p + dy * W + dx;
                acc += cbuf[wv][n] * spat_t[(size_t)q * 64 + lane];
            }
        }
        vbuf[wv][lane] = acc;
        float y1 = rb1;
#pragma unroll
        for (int k = 0; k < 64; ++k) y1 += w1t[k * 65 + lane] * vbuf[wv][k];
        float mean = wave_sum(y1) * (1.f / 64.f);
        float d = y1 - mean;
        float var = wave_sum(d * d) * (1.f / 64.f);
        float y = rg * d * rsqrtf(var + EPS_LN) + rbeta;   // no SiLU in output_proj
        vbuf[wv][lane] = y;
        float y2 = rb2;
#pragma unroll
        for (int k = 0; k < 64; ++k) y2 += w2t[k * 65 + lane] * vbuf[wv][k];
        out_t[(size_t)p * 64 + lane] = y2;
    }
}

// Kernel 4: transpose out_t [p][64] f32 -> out [B,C,H,W] f32 (coalesced both sides)
__global__ __launch_bounds__(256) void k4_transpose_out(
    const float* __restrict__ out_t, float* __restrict__ out)
{
    __shared__ float t[64 * 65];
    const int tid = threadIdx.x;
    const int p0 = blockIdx.x * 64;
    const int b = p0 / HW, hw0 = p0 - b * HW;
    for (int idx = tid; idx < 4096; idx += 256) {
        int i = idx >> 6, c = idx & 63;
        t[i * 65 + c] = out_t[(size_t)(p0 + i) * 64 + c];
    }
    __syncthreads();
    for (int idx = tid; idx < 4096; idx += 256) {
        int c = idx >> 6, i = idx & 63;
        out[(size_t)b * C * HW + (size_t)c * HW + hw0 + i] = t[i * 65 + c];
    }
}

extern "C" void kernel_launch(void* const* d_in, const int* in_sizes, int n_in,
                              void* d_out, int out_size, void* d_ws, size_t ws_size,
                              hipStream_t stream)
{
    const float* spatial  = (const float*)d_in[0];
    const float* semantic = (const float*)d_in[1];
    const float* rp_w1 = (const float*)d_in[2];
    const float* rp_b1 = (const float*)d_in[3];
    const float* rp_g  = (const float*)d_in[4];
    const float* rp_be = (const float*)d_in[5];
    const float* rp_w2 = (const float*)d_in[6];
    const float* rp_b2 = (const float*)d_in[7];
    const float* fx_w1 = (const float*)d_in[8];
    const float* fx_b1 = (const float*)d_in[9];
    const float* fx_g  = (const float*)d_in[10];
    const float* fx_be = (const float*)d_in[11];
    const float* fx_w2 = (const float*)d_in[12];
    const float* fx_b2 = (const float*)d_in[13];
    const float* op_w1 = (const float*)d_in[14];
    const float* op_b1 = (const float*)d_in[15];
    const float* op_g  = (const float*)d_in[16];
    const float* op_be = (const float*)d_in[17];
    const float* op_w2 = (const float*)d_in[18];
    const float* op_b2 = (const float*)d_in[19];
    const float* sigma = (const float*)d_in[20];

    float* ws = (float*)d_ws;
    float* sem_t  = ws;
    float* px_t   = sem_t  + (size_t)NPIX * 64;
    float* spat_t = px_t   + (size_t)NPIX * 64;
    float* comb_g = spat_t + (size_t)NPIX * 64;
    float* out_t  = comb_g + (size_t)NPIX * N2;

    k1_range_proj<<<NPIX / 64, 512, 0, stream>>>(
        semantic, spatial, rp_w1, rp_b1, rp_g, rp_be, rp_w2, rp_b2,
        sem_t, spat_t, px_t);
    k2_combined<<<NPIX / 32, 256, 0, stream>>>(
        px_t, sem_t, fx_w1, fx_b1, fx_g, fx_be, fx_w2, fx_b2, sigma, comb_g);
    k3_output<<<NPIX / 32, 256, 0, stream>>>(
        spat_t, comb_g, op_w1, op_b1, op_g, op_be, op_w2, op_b2, out_t);
    k4_transpose_out<<<NPIX / 64, 256, 0, stream>>>(out_t, (float*)d_out);
}

// Round 3
// 419.811 us; speedup vs baseline: 1.4272x; 1.4272x over previous
//
#include <hip/hip_runtime.h>
#include <hip/hip_bf16.h>

constexpr int B = 2, C = 64, H = 112, W = 112, N2 = 49;
constexpr int HW = H * W;          // 12544
constexpr int NPIX = B * HW;       // 25088
constexpr int TILES_X = W / 8;     // 14
constexpr int TILES_PER_IMG = (H / 8) * (W / 8);  // 196
constexpr int NBLK = B * TILES_PER_IMG;           // 392
constexpr float EPS_LN = 1e-6f, EPS_NORM = 1e-7f;

__device__ __forceinline__ float rcp_fast(float x) { return __builtin_amdgcn_rcpf(x); }
__device__ __forceinline__ float sigmoid_f(float x) { return rcp_fast(1.f + __expf(-x)); }

// ---------------------------------------------------------------------------
// k1: px = range_proj(semantic), lane=pixel (8x8 tile per wave), no shuffles.
// Writes px_t[p][64] (coalesced via LDS pitch-65 transpose) and sqnorm[p].
// ---------------------------------------------------------------------------
__global__ __launch_bounds__(64) void k1_range_proj(
    const float* __restrict__ sem,
    const float* __restrict__ w1, const float* __restrict__ b1,
    const float* __restrict__ g,  const float* __restrict__ be,
    const float* __restrict__ w2, const float* __restrict__ b2,
    float* __restrict__ px_t, float* __restrict__ sqnorm)
{
    __shared__ __align__(16) float f_scr[64 * 64];   // [o][lane]
    __shared__ __align__(16) float px_scr[64 * 65];  // [o][lane] pitch 65

    const int lane = threadIdx.x;
    const int blk = blockIdx.x;
    const int b  = blk / TILES_PER_IMG;
    const int t  = blk - b * TILES_PER_IMG;
    const int ty = t / TILES_X, tx = t - ty * TILES_X;
    const int h = ty * 8 + (lane >> 3), w = tx * 8 + (lane & 7);
    const int hw = h * W + w;

    float sv[64];
#pragma unroll
    for (int k = 0; k < 64; ++k) sv[k] = sem[(size_t)(b * 64 + k) * HW + hw];

    float macc = 0.f, sacc = 0.f;
    for (int o = 0; o < 64; ++o) {              // dynamic loop: small I-footprint
        float a0 = 0, a1 = 0, a2 = 0, a3 = 0;
        const float* wr = &w1[o * 64];
#pragma unroll
        for (int k = 0; k < 64; k += 4) {
            a0 += wr[k + 0] * sv[k + 0];
            a1 += wr[k + 1] * sv[k + 1];
            a2 += wr[k + 2] * sv[k + 2];
            a3 += wr[k + 3] * sv[k + 3];
        }
        float f = (a0 + a1) + (a2 + a3) + b1[o];
        f_scr[o * 64 + lane] = f;               // bank = lane%32: 2-way (free)
        macc += f; sacc += f * f;
    }
    __syncthreads();
    float mean = macc * (1.f / 64.f);
    float var  = sacc * (1.f / 64.f) - mean * mean;   // E[x^2]-m^2 (mean~0, safe)
    float rstd = rsqrtf(var + EPS_LN);

    float s[64];
#pragma unroll
    for (int k = 0; k < 64; ++k) {
        float y = g[k] * (f_scr[k * 64 + lane] - mean) * rstd + be[k];
        s[k] = y * sigmoid_f(y);                // SiLU
    }
    float sq = 0.f;
    for (int o = 0; o < 64; ++o) {
        float a0 = 0, a1 = 0, a2 = 0, a3 = 0;
        const float* wr = &w2[o * 64];
#pragma unroll
        for (int k = 0; k < 64; k += 4) {
            a0 += wr[k + 0] * s[k + 0];
            a1 += wr[k + 1] * s[k + 1];
            a2 += wr[k + 2] * s[k + 2];
            a3 += wr[k + 3] * s[k + 3];
        }
        float z = (a0 + a1) + (a2 + a3) + b2[o];
        sq += z * z;
        px_scr[o * 65 + lane] = z;              // bank (o+lane)%32: conflict-free
    }
    __syncthreads();
    sqnorm[(size_t)b * HW + hw] = sq;
    // transpose out: iteration i stores pixel i's full channel row, lane=channel
    for (int i = 0; i < 64; ++i) {
        int hwi = (ty * 8 + (i >> 3)) * W + tx * 8 + (i & 7);
        px_t[(size_t)((size_t)b * HW + hwi) * 64 + lane] = px_scr[lane * 65 + i];
    }
}

// ---------------------------------------------------------------------------
// k2: bilateral weights + gated fixup + normalize. lane=pixel.
// Halo in LDS with XOR-swizzled 16B chunks: element (r, c) lives at
// (r<<6) + (c ^ ((r&7)<<2))  -> b128 reads at fixed chunk hit all 8 bank quads.
// ---------------------------------------------------------------------------
__global__ __launch_bounds__(64) void k2_combined(
    const float* __restrict__ px_t, const float* __restrict__ sqnorm,
    const float* __restrict__ sem,
    const float* __restrict__ fw1, const float* __restrict__ fb1,
    const float* __restrict__ fg,  const float* __restrict__ fbe,
    const float* __restrict__ fw2, const float* __restrict__ fb2,
    const float* __restrict__ sigma_, float* __restrict__ comb_g)
{
    __shared__ __align__(16) float halo[196 * 64];     // 50176 B, swizzled
    __shared__ __align__(16) float sqn_l[196];
    __shared__ __align__(16) float comb_scr[49 * 64];  // 12544 B
    float* f_scr = halo;   // halo dead after dot phase; reuse for fixup scratch

    const int lane = threadIdx.x;
    const int blk = blockIdx.x;
    const int b  = blk / TILES_PER_IMG;
    const int t  = blk - b * TILES_PER_IMG;
    const int ty = t / TILES_X, tx = t - ty * TILES_X;
    const int h = ty * 8 + (lane >> 3), w = tx * 8 + (lane & 7);
    const int hw = h * W + w;
    const int p = b * HW + hw;

    // stage px halo rows (lane = channel; coalesced 256B row loads)
    {
        int ry = 0, rx = 0;
        for (int r = 0; r < 196; ++r) {
            int hh = ty * 8 - 3 + ry, ww = tx * 8 - 3 + rx;
            bool valid = (unsigned)hh < (unsigned)H && (unsigned)ww < (unsigned)W;
            float v = 0.f;
            if (valid) v = px_t[(size_t)((size_t)b * HW + hh * W + ww) * 64 + lane];
            halo[(r << 6) + (lane ^ ((r & 7) << 2))] = v;
            if (++rx == 14) { rx = 0; ++ry; }
        }
        for (int rr = lane; rr < 196; rr += 64) {   // sqnorm halo, lane = row
            int ryv = (rr * 2341) >> 15;            // exact /14 for rr<256
            int rxv = rr - ryv * 14;
            int hh = ty * 8 - 3 + ryv, ww = tx * 8 - 3 + rxv;
            bool valid = (unsigned)hh < (unsigned)H && (unsigned)ww < (unsigned)W;
            sqn_l[rr] = valid ? sqnorm[(size_t)b * HW + hh * W + ww] : 0.f;
        }
    }
    __syncthreads();

    const int rbase = (lane >> 3) * 14 + (lane & 7);
    const int rp = rbase + 45;                       // own halo row (dy=dx=0)
    const int ctr_bx = (rp << 6) ^ ((rp & 7) << 2);
    float cv[64];
#pragma unroll
    for (int kc = 0; kc < 16; ++kc) {
        float4 v = *(const float4*)&halo[ctr_bx ^ (kc << 2)];
        cv[4 * kc] = v.x; cv[4 * kc + 1] = v.y; cv[4 * kc + 2] = v.z; cv[4 * kc + 3] = v.w;
    }
    const float sqc = sqn_l[rp];
    const float sigma = sigma_[0];
    const float inv2s2 = rcp_fast(2.f * sigma * sigma);

    {
        int ry = 0, rx = 0;
        for (int n = 0; n < 49; ++n) {
            int rn = rbase + ry * 14 + rx;
            int bx = (rn << 6) ^ ((rn & 7) << 2);
            float d0 = 0, d1 = 0, d2 = 0, d3 = 0;
#pragma unroll
            for (int kc = 0; kc < 16; ++kc) {
                float4 v = *(const float4*)&halo[bx ^ (kc << 2)];
                d0 += v.x * cv[4 * kc];     d1 += v.y * cv[4 * kc + 1];
                d2 += v.z * cv[4 * kc + 2]; d3 += v.w * cv[4 * kc + 3];
            }
            float dot = (d0 + d1) + (d2 + d3);
            float dist2 = fmaxf(sqn_l[rn] + sqc - 2.f * dot, 0.f);
            int dy = ry - 3, dx = rx - 3;
            bool valid = (unsigned)(h + dy) < (unsigned)H && (unsigned)(w + dx) < (unsigned)W;
            float d2n = (float)(dy * dy + dx * dx);
            float wgt = valid ? __expf(-(dist2 * (1.f / 128.f) + d2n * inv2s2)) : 0.f;
            comb_scr[n * 64 + lane] = wgt;
            if (++rx == 7) { rx = 0; ++ry; }
        }
    }
    __syncthreads();

    float cb[49];
#pragma unroll
    for (int n = 0; n < 49; ++n) cb[n] = comb_scr[n * 64 + lane];
    float sv[64];
#pragma unroll
    for (int k = 0; k < 64; ++k) sv[k] = sem[(size_t)(b * 64 + k) * HW + hw];

    // fixup conv1: [49 x 113] (inputs: 49 combined then 64 semantic)
    float macc = 0.f, sacc = 0.f;
    for (int o = 0; o < 49; ++o) {
        float a0 = 0, a1 = 0, a2 = 0, a3 = 0;
        const float* wr = &fw1[o * 113];
#pragma unroll
        for (int k = 0; k < 48; k += 4) {
            a0 += wr[k + 0] * cb[k + 0]; a1 += wr[k + 1] * cb[k + 1];
            a2 += wr[k + 2] * cb[k + 2]; a3 += wr[k + 3] * cb[k + 3];
        }
        a0 += wr[48] * cb[48];
        const float* ws2 = wr + 49;
#pragma unroll
        for (int k = 0; k < 64; k += 4) {
            a0 += ws2[k + 0] * sv[k + 0]; a1 += ws2[k + 1] * sv[k + 1];
            a2 += ws2[k + 2] * sv[k + 2]; a3 += ws2[k + 3] * sv[k + 3];
        }
        float f = (a0 + a1) + (a2 + a3) + fb1[o];
        f_scr[o * 64 + lane] = f;
        macc += f; sacc += f * f;
    }
    __syncthreads();
    float mean = macc * (1.f / 49.f);
    float var  = sacc * (1.f / 49.f) - mean * mean;
    float rstd = rsqrtf(var + EPS_LN);
    float s[49];
#pragma unroll
    for (int k = 0; k < 49; ++k) {
        float y = fg[k] * (f_scr[k * 64 + lane] - mean) * rstd + fbe[k];
        s[k] = y * sigmoid_f(y);
    }
    float tot = 0.f;
    for (int o = 0; o < 49; ++o) {
        float a0 = 0, a1 = 0, a2 = 0, a3 = 0;
        const float* wr = &fw2[o * 49];
#pragma unroll
        for (int k = 0; k < 48; k += 4) {
            a0 += wr[k + 0] * s[k + 0]; a1 += wr[k + 1] * s[k + 1];
            a2 += wr[k + 2] * s[k + 2]; a3 += wr[k + 3] * s[k + 3];
        }
        a0 += wr[48] * s[48];
        float fo = (a0 + a1) + (a2 + a3) + fb2[o];
        float gate = 1.f + sigmoid_f(fo);
        float cvv = comb_scr[o * 64 + lane] * gate;   // same-wave DS ops stay ordered
        comb_scr[o * 64 + lane] = cvv;
        tot += cvv;
    }
    __syncthreads();
    float inv = rcp_fast(tot + EPS_NORM);
    for (int n = 0; n < 49; ++n)
        comb_g[(size_t)n * NPIX + p] = comb_scr[n * 64 + lane] * inv;
}

// ---------------------------------------------------------------------------
// k3: weighted neighborhood reduction + output_proj, fused transpose-out.
// Stages spatial halo straight from global [B,C,H,W] (spat_t eliminated).
// ---------------------------------------------------------------------------
__global__ __launch_bounds__(64) void k3_output(
    const float* __restrict__ spat, const float* __restrict__ comb_g,
    const float* __restrict__ w1, const float* __restrict__ b1,
    const float* __restrict__ g,  const float* __restrict__ be,
    const float* __restrict__ w2, const float* __restrict__ b2,
    float* __restrict__ out)
{
    __shared__ __align__(16) float halo[196 * 64];
    __shared__ __align__(16) float comb_scr[49 * 64];
    float* f_scr = halo;   // reuse after neighborhood phase

    const int lane = threadIdx.x;
    const int blk = blockIdx.x;
    const int b  = blk / TILES_PER_IMG;
    const int t  = blk - b * TILES_PER_IMG;
    const int ty = t / TILES_X, tx = t - ty * TILES_X;
    const int h = ty * 8 + (lane >> 3), w = tx * 8 + (lane & 7);
    const int hw = h * W + w;
    const int p = b * HW + hw;

    // stage spat halo: lane = halo row, loop channels (semi-coalesced source)
    for (int rb = 0; rb < 4; ++rb) {
        int rr = rb * 64 + lane;
        bool act = rr < 196;
        int ryv = (rr * 2341) >> 15;
        int rxv = rr - ryv * 14;
        int hh = ty * 8 - 3 + ryv, ww = tx * 8 - 3 + rxv;
        bool valid = act && (unsigned)hh < (unsigned)H && (unsigned)ww < (unsigned)W;
        int soff = hh * W + ww;
        int wbase = rr << 6, sw8 = (rr & 7) << 2;
        for (int c = 0; c < 64; ++c) {
            float v = valid ? spat[(size_t)(b * 64 + c) * HW + soff] : 0.f;
            if (act) halo[wbase + (c ^ sw8)] = v;
        }
    }
    for (int n = 0; n < 49; ++n)
        comb_scr[n * 64 + lane] = comb_g[(size_t)n * NPIX + p];
    __syncthreads();

    const int rbase = (lane >> 3) * 14 + (lane & 7);
    float acc[64];
#pragma unroll
    for (int k = 0; k < 64; ++k) acc[k] = 0.f;
    {
        int ry = 0, rx = 0;
        for (int n = 0; n < 49; ++n) {
            float cn = comb_scr[n * 64 + lane];
            int rn = rbase + ry * 14 + rx;
            int bx = (rn << 6) ^ ((rn & 7) << 2);
#pragma unroll
            for (int kc = 0; kc < 16; ++kc) {
                float4 v = *(const float4*)&halo[bx ^ (kc << 2)];
                acc[4 * kc]     += cn * v.x; acc[4 * kc + 1] += cn * v.y;
                acc[4 * kc + 2] += cn * v.z; acc[4 * kc + 3] += cn * v.w;
            }
            if (++rx == 7) { rx = 0; ++ry; }
        }
    }
    __syncthreads();   // halo reads done; f_scr (alias) writes may begin

    float macc = 0.f, sacc = 0.f;
    for (int o = 0; o < 64; ++o) {
        float a0 = 0, a1 = 0, a2 = 0, a3 = 0;
        const float* wr = &w1[o * 64];
#pragma unroll
        for (int k = 0; k < 64; k += 4) {
            a0 += wr[k + 0] * acc[k + 0]; a1 += wr[k + 1] * acc[k + 1];
            a2 += wr[k + 2] * acc[k + 2]; a3 += wr[k + 3] * acc[k + 3];
        }
        float f = (a0 + a1) + (a2 + a3) + b1[o];
        f_scr[o * 64 + lane] = f;
        macc += f; sacc += f * f;
    }
    __syncthreads();
    float mean = macc * (1.f / 64.f);
    float var  = sacc * (1.f / 64.f) - mean * mean;
    float rstd = rsqrtf(var + EPS_LN);
    float yv[64];
#pragma unroll
    for (int k = 0; k < 64; ++k)
        yv[k] = g[k] * (f_scr[k * 64 + lane] - mean) * rstd + be[k];

    for (int o = 0; o < 64; ++o) {
        float a0 = 0, a1 = 0, a2 = 0, a3 = 0;
        const float* wr = &w2[o * 64];
#pragma unroll
        for (int k = 0; k < 64; k += 4) {
            a0 += wr[k + 0] * yv[k + 0]; a1 += wr[k + 1] * yv[k + 1];
            a2 += wr[k + 2] * yv[k + 2]; a3 += wr[k + 3] * yv[k + 3];
        }
        float z = (a0 + a1) + (a2 + a3) + b2[o];
        out[(size_t)(b * 64 + o) * HW + hw] = z;   // fused transpose-out
    }
}

extern "C" void kernel_launch(void* const* d_in, const int* in_sizes, int n_in,
                              void* d_out, int out_size, void* d_ws, size_t ws_size,
                              hipStream_t stream)
{
    const float* spatial  = (const float*)d_in[0];
    const float* semantic = (const float*)d_in[1];
    const float* rp_w1 = (const float*)d_in[2];
    const float* rp_b1 = (const float*)d_in[3];
    const float* rp_g  = (const float*)d_in[4];
    const float* rp_be = (const float*)d_in[5];
    const float* rp_w2 = (const float*)d_in[6];
    const float* rp_b2 = (const float*)d_in[7];
    const float* fx_w1 = (const float*)d_in[8];
    const float* fx_b1 = (const float*)d_in[9];
    const float* fx_g  = (const float*)d_in[10];
    const float* fx_be = (const float*)d_in[11];
    const float* fx_w2 = (const float*)d_in[12];
    const float* fx_b2 = (const float*)d_in[13];
    const float* op_w1 = (const float*)d_in[14];
    const float* op_b1 = (const float*)d_in[15];
    const float* op_g  = (const float*)d_in[16];
    const float* op_be = (const float*)d_in[17];
    const float* op_w2 = (const float*)d_in[18];
    const float* op_b2 = (const float*)d_in[19];
    const float* sigma = (const float*)d_in[20];

    float* ws = (float*)d_ws;
    float* px_t   = ws;
    float* sqnorm = px_t + (size_t)NPIX * 64;
    float* comb_g = sqnorm + (size_t)NPIX;

    k1_range_proj<<<NBLK, 64, 0, stream>>>(
        semantic, rp_w1, rp_b1, rp_g, rp_be, rp_w2, rp_b2, px_t, sqnorm);
    k2_combined<<<NBLK, 64, 0, stream>>>(
        px_t, sqnorm, semantic, fx_w1, fx_b1, fx_g, fx_be, fx_w2, fx_b2, sigma, comb_g);
    k3_output<<<NBLK, 64, 0, stream>>>(
        spatial, comb_g, op_w1, op_b1, op_g, op_be, op_w2, op_b2, (float*)d_out);
}

// Round 4
// 274.610 us; speedup vs baseline: 2.1818x; 1.5288x over previous
//
#include <hip/hip_runtime.h>

constexpr int B = 2, C = 64, H = 112, W = 112;
constexpr int HW = H * W;          // 12544
constexpr int NPIX = B * HW;       // 25088
constexpr int TILES_X = 14;
constexpr int TILES_PER_IMG = 196;
constexpr int NBLK = B * TILES_PER_IMG;   // 392
constexpr float EPS_LN = 1e-6f, EPS_NORM = 1e-7f;

__device__ __forceinline__ float rcp_fast(float x) { return __builtin_amdgcn_rcpf(x); }
__device__ __forceinline__ float sigmoid_f(float x) { return rcp_fast(1.f + __expf(-x)); }

// ---------------------------------------------------------------------------
// k1: px = range_proj(semantic). 256 threads / 8x8 tile; 4 waves split the 64
// output channels (16 each). lane = pixel. Cross-wave LN via LDS partials.
// Outputs px_t[p][64] (pixel-major) + sqnorm[p].
// ---------------------------------------------------------------------------
__global__ __launch_bounds__(256) void k1_range_proj(
    const float* __restrict__ sem,
    const float* __restrict__ w1, const float* __restrict__ b1,
    const float* __restrict__ g,  const float* __restrict__ be,
    const float* __restrict__ w2, const float* __restrict__ b2,
    float* __restrict__ px_t, float* __restrict__ sqnorm)
{
    __shared__ float f_scr[64 * 64];    // [o][pix]
    __shared__ float px_scr[64 * 65];   // [o][pix] pitch 65 (transpose-out)
    __shared__ float pm[4 * 64], ps[4 * 64], p2[4 * 64];

    const int tid = threadIdx.x, lane = tid & 63, wv = tid >> 6;
    const int blk = blockIdx.x, b = blk / TILES_PER_IMG, t = blk - b * TILES_PER_IMG;
    const int ty = t / TILES_X, tx = t - ty * TILES_X;
    const int h = ty * 8 + (lane >> 3), w = tx * 8 + (lane & 7);
    const int hw = h * W + w;

    float sv[64];
#pragma unroll
    for (int k = 0; k < 64; ++k) sv[k] = sem[(size_t)(b * 64 + k) * HW + hw];

    const int o0 = wv * 16;
    float macc = 0.f, sacc = 0.f;
    for (int j = 0; j < 16; ++j) {
        int o = o0 + j; const float* wr = &w1[o * 64];
        float a0 = 0, a1 = 0, a2 = 0, a3 = 0;
#pragma unroll
        for (int k = 0; k < 64; k += 4) {
            a0 += wr[k] * sv[k];       a1 += wr[k + 1] * sv[k + 1];
            a2 += wr[k + 2] * sv[k + 2]; a3 += wr[k + 3] * sv[k + 3];
        }
        float f = (a0 + a1) + (a2 + a3) + b1[o];
        f_scr[o * 64 + lane] = f;      // bank=lane%32: 2-way, free
        macc += f; sacc += f * f;
    }
    pm[wv * 64 + lane] = macc; ps[wv * 64 + lane] = sacc;
    __syncthreads();
    float m  = (pm[lane] + pm[64 + lane] + pm[128 + lane] + pm[192 + lane]) * (1.f / 64.f);
    float va = (ps[lane] + ps[64 + lane] + ps[128 + lane] + ps[192 + lane]) * (1.f / 64.f) - m * m;
    float rstd = rsqrtf(va + EPS_LN);

    float s[64];
#pragma unroll
    for (int k = 0; k < 64; ++k) {
        float y = g[k] * (f_scr[k * 64 + lane] - m) * rstd + be[k];
        s[k] = y * sigmoid_f(y);
    }
    float sq = 0.f;
    for (int j = 0; j < 16; ++j) {
        int o = o0 + j; const float* wr = &w2[o * 64];
        float a0 = 0, a1 = 0, a2 = 0, a3 = 0;
#pragma unroll
        for (int k = 0; k < 64; k += 4) {
            a0 += wr[k] * s[k];        a1 += wr[k + 1] * s[k + 1];
            a2 += wr[k + 2] * s[k + 2]; a3 += wr[k + 3] * s[k + 3];
        }
        float z = (a0 + a1) + (a2 + a3) + b2[o];
        px_scr[o * 65 + lane] = z;     // bank=(o+lane)%32: conflict-free
        sq += z * z;
    }
    p2[wv * 64 + lane] = sq;
    __syncthreads();
    if (wv == 0)
        sqnorm[(size_t)b * HW + hw] = p2[lane] + p2[64 + lane] + p2[128 + lane] + p2[192 + lane];
    // transpose-out: wave wv stores pixels o0..o0+15; lane = channel
    for (int j = 0; j < 16; ++j) {
        int ii = o0 + j;
        int hwi = (ty * 8 + (ii >> 3)) * W + tx * 8 + (ii & 7);
        px_t[((size_t)b * HW + hwi) * 64 + lane] = px_scr[lane * 65 + ii];  // (lane+ii)%32: cf
    }
}

// ---------------------------------------------------------------------------
// k23: fused bilateral weights + gated fixup + normalize + neighborhood
// reduction + output_proj. 256 threads / 8x8 tile.
// Halo layout (both stagings): element (r, c) at (r<<6) | ((c ^ ((r&7)<<2)))
// -> float4 reads/writes at the 1KB/128B LDS floor; pixel-major staging writes
// conflict-free; channel-major staging uses quad-per-thread b128 writes.
// ---------------------------------------------------------------------------
__global__ __launch_bounds__(256) void k23_fused(
    const float* __restrict__ px_t, const float* __restrict__ sqnorm,
    const float* __restrict__ sem,  const float* __restrict__ spat,
    const float* __restrict__ fw1, const float* __restrict__ fb1,
    const float* __restrict__ fg,  const float* __restrict__ fbe,
    const float* __restrict__ fw2, const float* __restrict__ fb2,
    const float* __restrict__ w1, const float* __restrict__ b1,
    const float* __restrict__ g,  const float* __restrict__ be,
    const float* __restrict__ w2, const float* __restrict__ b2,
    const float* __restrict__ sigma_, float* __restrict__ out)
{
    __shared__ __align__(16) float halo[196 * 64];      // 50176 B (aliased below)
    __shared__ __align__(16) float comb_scr[49 * 64];   // 12544 B
    __shared__ float sqn_l[196];
    __shared__ float pm[4 * 64], ps[4 * 64], pt[4 * 64];

    const int tid = threadIdx.x, lane = tid & 63, wv = tid >> 6;
    const int blk = blockIdx.x, b = blk / TILES_PER_IMG, t = blk - b * TILES_PER_IMG;
    const int ty = t / TILES_X, tx = t - ty * TILES_X;
    const int h = ty * 8 + (lane >> 3), w = tx * 8 + (lane & 7);
    const int hw = h * W + w;
    const int h0 = ty * 8 - 3, w0 = tx * 8 - 3;

    // ---- phase 1: stage px halo (pixel-major source: coalesced, cf writes) ----
    for (int i = 0; i < 49; ++i) {
        int idx = i * 256 + tid; int r = idx >> 6, c = idx & 63;
        int ry = (r * 2341) >> 15, rx = r - ry * 14;     // exact /14 for r<256
        int hh = h0 + ry, ww = w0 + rx;
        bool valid = (unsigned)hh < (unsigned)H && (unsigned)ww < (unsigned)W;
        float v = 0.f;
        if (valid) v = px_t[((size_t)b * HW + hh * W + ww) * 64 + c];
        halo[(r << 6) | (c ^ ((r & 7) << 2))] = v;
    }
    if (tid < 196) {
        int ry = (tid * 2341) >> 15, rx = tid - ry * 14;
        int hh = h0 + ry, ww = w0 + rx;
        bool valid = (unsigned)hh < (unsigned)H && (unsigned)ww < (unsigned)W;
        float v = 0.f;
        if (valid) v = sqnorm[(size_t)b * HW + hh * W + ww];
        sqn_l[tid] = v;
    }
    __syncthreads();

    // ---- phase 2: bilateral weights, neighbors split across waves ----
    const int rbase = (lane >> 3) * 14 + (lane & 7);
    const int rp = rbase + 45;
    const int ctr = (rp << 6) ^ ((rp & 7) << 2);
    float cv[64];
#pragma unroll
    for (int q = 0; q < 16; ++q) {
        float4 v = *(const float4*)&halo[ctr ^ (q << 2)];
        cv[4 * q] = v.x; cv[4 * q + 1] = v.y; cv[4 * q + 2] = v.z; cv[4 * q + 3] = v.w;
    }
    const float sqc = sqn_l[rp];
    const float sg_ = sigma_[0];
    const float inv2s2 = rcp_fast(2.f * sg_ * sg_);
    for (int n = wv; n < 49; n += 4) {
        int ryn = n / 7, rxn = n - ryn * 7;
        int dy = ryn - 3, dx = rxn - 3;
        int rn = rbase + ryn * 14 + rxn;
        int bx = (rn << 6) ^ ((rn & 7) << 2);
        float d0 = 0, d1 = 0, d2 = 0, d3 = 0;
#pragma unroll
        for (int q = 0; q < 16; ++q) {
            float4 v = *(const float4*)&halo[bx ^ (q << 2)];
            d0 += v.x * cv[4 * q];     d1 += v.y * cv[4 * q + 1];
            d2 += v.z * cv[4 * q + 2]; d3 += v.w * cv[4 * q + 3];
        }
        float dot = (d0 + d1) + (d2 + d3);
        float dist2 = fmaxf(sqn_l[rn] + sqc - 2.f * dot, 0.f);
        bool valid = (unsigned)(h + dy) < (unsigned)H && (unsigned)(w + dx) < (unsigned)W;
        float d2n = (float)(dy * dy + dx * dx);
        comb_scr[n * 64 + lane] = valid ? __expf(-(dist2 * (1.f / 128.f) + d2n * inv2s2)) : 0.f;
    }
    __syncthreads();

    // ---- phase 3: gated fixup, outputs split across waves ----
    float cb[49];
#pragma unroll
    for (int n = 0; n < 49; ++n) cb[n] = comb_scr[n * 64 + lane];
    float svv[64];
#pragma unroll
    for (int k = 0; k < 64; ++k) svv[k] = sem[(size_t)(b * 64 + k) * HW + hw];
    float* f_scr = halo;                 // px halo dead after phase 2
    float macc = 0.f, sacc = 0.f;
    for (int o = wv; o < 49; o += 4) {
        const float* wr = &fw1[o * 113];
        float a0 = 0, a1 = 0, a2 = 0, a3 = 0;
#pragma unroll
        for (int k = 0; k < 48; k += 4) {
            a0 += wr[k] * cb[k];       a1 += wr[k + 1] * cb[k + 1];
            a2 += wr[k + 2] * cb[k + 2]; a3 += wr[k + 3] * cb[k + 3];
        }
        a0 += wr[48] * cb[48];
        const float* wr2 = wr + 49;
#pragma unroll
        for (int k = 0; k < 64; k += 4) {
            a0 += wr2[k] * svv[k];       a1 += wr2[k + 1] * svv[k + 1];
            a2 += wr2[k + 2] * svv[k + 2]; a3 += wr2[k + 3] * svv[k + 3];
        }
        float f = (a0 + a1) + (a2 + a3) + fb1[o];
        f_scr[o * 64 + lane] = f;
        macc += f; sacc += f * f;
    }
    pm[wv * 64 + lane] = macc; ps[wv * 64 + lane] = sacc;
    __syncthreads();
    {
        float m  = (pm[lane] + pm[64 + lane] + pm[128 + lane] + pm[192 + lane]) * (1.f / 49.f);
        float va = (ps[lane] + ps[64 + lane] + ps[128 + lane] + ps[192 + lane]) * (1.f / 49.f) - m * m;
        float rstd = rsqrtf(va + EPS_LN);
        float s[49];
#pragma unroll
        for (int k = 0; k < 49; ++k) {
            float y = fg[k] * (f_scr[k * 64 + lane] - m) * rstd + fbe[k];
            s[k] = y * sigmoid_f(y);
        }
        float tacc = 0.f;
        for (int o = wv; o < 49; o += 4) {
            const float* wr = &fw2[o * 49];
            float a0 = 0, a1 = 0, a2 = 0, a3 = 0;
#pragma unroll
            for (int k = 0; k < 48; k += 4) {
                a0 += wr[k] * s[k];       a1 += wr[k + 1] * s[k + 1];
                a2 += wr[k + 2] * s[k + 2]; a3 += wr[k + 3] * s[k + 3];
            }
            a0 += wr[48] * s[48];
            float fo = (a0 + a1) + (a2 + a3) + fb2[o];
            float gate = 1.f + sigmoid_f(fo);
            float cx = comb_scr[o * 64 + lane] * gate;   // same rows this wave wrote
            comb_scr[o * 64 + lane] = cx;
            tacc += cx;
        }
        pt[wv * 64 + lane] = tacc;
    }
    __syncthreads();   // all f_scr reads done -> halo restage is safe
    const float inv = rcp_fast(pt[lane] + pt[64 + lane] + pt[128 + lane] + pt[192 + lane] + EPS_NORM);

    // ---- phase 4: restage halo with spatial (channel-major source) ----
    // quad-per-thread: 4 coalesced b32 loads (consecutive lanes = consecutive
    // halo pixels) + one b128 swizzled write at the LDS floor (no 8-way scalar).
    for (int i = 0; i < 13; ++i) {
        int idx = i * 256 + tid;          // idx = cq*196 + r
        if (idx < 3136) {
            int cq = idx / 196, r = idx - cq * 196;
            int ry = (r * 2341) >> 15, rx = r - ry * 14;
            int hh = h0 + ry, ww = w0 + rx;
            bool valid = (unsigned)hh < (unsigned)H && (unsigned)ww < (unsigned)W;
            float4 v = make_float4(0.f, 0.f, 0.f, 0.f);
            if (valid) {
                const float* sp = &spat[(size_t)(b * 64 + cq * 4) * HW + hh * W + ww];
                v.x = sp[0]; v.y = sp[HW]; v.z = sp[2 * HW]; v.w = sp[3 * HW];
            }
            *(float4*)&halo[(r << 6) | ((cq ^ (r & 7)) << 2)] = v;
        }
    }
    __syncthreads();

    // ---- phase 5: weighted neighborhood reduction, channels split across waves ----
    const int c0 = wv * 16;
    float acc[16];
#pragma unroll
    for (int j = 0; j < 16; ++j) acc[j] = 0.f;
    for (int n = 0; n < 49; ++n) {
        int ryn = n / 7, rxn = n - ryn * 7;
        int rn = rbase + ryn * 14 + rxn;
        int bx = (rn << 6) ^ ((rn & 7) << 2);
        float cn = comb_scr[n * 64 + lane] * inv;
#pragma unroll
        for (int q = 0; q < 4; ++q) {
            float4 v = *(const float4*)&halo[bx ^ (((c0 >> 2) + q) << 2)];
            acc[4 * q]     += cn * v.x; acc[4 * q + 1] += cn * v.y;
            acc[4 * q + 2] += cn * v.z; acc[4 * q + 3] += cn * v.w;
        }
    }
    __syncthreads();   // halo reads done -> av/f2 aliases safe

    // ---- phase 6: output_proj ----
    float* av = halo;                 // [c][pix] 64x64
    float* f2 = halo + 4096;          // [o][pix] 64x64
    for (int j = 0; j < 16; ++j) av[(c0 + j) * 64 + lane] = acc[j];
    __syncthreads();
    float xv[64];
#pragma unroll
    for (int k = 0; k < 64; ++k) xv[k] = av[k * 64 + lane];
    macc = 0.f; sacc = 0.f;
    for (int j = 0; j < 16; ++j) {
        int o = c0 + j; const float* wr = &w1[o * 64];
        float a0 = 0, a1 = 0, a2 = 0, a3 = 0;
#pragma unroll
        for (int k = 0; k < 64; k += 4) {
            a0 += wr[k] * xv[k];       a1 += wr[k + 1] * xv[k + 1];
            a2 += wr[k + 2] * xv[k + 2]; a3 += wr[k + 3] * xv[k + 3];
        }
        float f = (a0 + a1) + (a2 + a3) + b1[o];
        f2[o * 64 + lane] = f;
        macc += f; sacc += f * f;
    }
    pm[wv * 64 + lane] = macc; ps[wv * 64 + lane] = sacc;
    __syncthreads();
    float m  = (pm[lane] + pm[64 + lane] + pm[128 + lane] + pm[192 + lane]) * (1.f / 64.f);
    float va = (ps[lane] + ps[64 + lane] + ps[128 + lane] + ps[192 + lane]) * (1.f / 64.f) - m * m;
    float rstd = rsqrtf(va + EPS_LN);
    float yv[64];
#pragma unroll
    for (int k = 0; k < 64; ++k)
        yv[k] = g[k] * (f2[k * 64 + lane] - m) * rstd + be[k];
    for (int j = 0; j < 16; ++j) {
        int o = c0 + j; const float* wr = &w2[o * 64];
        float a0 = 0, a1 = 0, a2 = 0, a3 = 0;
#pragma unroll
        for (int k = 0; k < 64; k += 4) {
            a0 += wr[k] * yv[k];       a1 += wr[k + 1] * yv[k + 1];
            a2 += wr[k + 2] * yv[k + 2]; a3 += wr[k + 3] * yv[k + 3];
        }
        float z = (a0 + a1) + (a2 + a3) + b2[o];
        out[(size_t)(b * 64 + o) * HW + hw] = z;
    }
}

extern "C" void kernel_launch(void* const* d_in, const int* in_sizes, int n_in,
                              void* d_out, int out_size, void* d_ws, size_t ws_size,
                              hipStream_t stream)
{
    const float* spatial  = (const float*)d_in[0];
    const float* semantic = (const float*)d_in[1];
    const float* rp_w1 = (const float*)d_in[2];
    const float* rp_b1 = (const float*)d_in[3];
    const float* rp_g  = (const float*)d_in[4];
    const float* rp_be = (const float*)d_in[5];
    const float* rp_w2 = (const float*)d_in[6];
    const float* rp_b2 = (const float*)d_in[7];
    const float* fx_w1 = (const float*)d_in[8];
    const float* fx_b1 = (const float*)d_in[9];
    const float* fx_g  = (const float*)d_in[10];
    const float* fx_be = (const float*)d_in[11];
    const float* fx_w2 = (const float*)d_in[12];
    const float* fx_b2 = (const float*)d_in[13];
    const float* op_w1 = (const float*)d_in[14];
    const float* op_b1 = (const float*)d_in[15];
    const float* op_g  = (const float*)d_in[16];
    const float* op_be = (const float*)d_in[17];
    const float* op_w2 = (const float*)d_in[18];
    const float* op_b2 = (const float*)d_in[19];
    const float* sigma = (const float*)d_in[20];

    float* ws = (float*)d_ws;
    float* px_t   = ws;
    float* sqnorm = px_t + (size_t)NPIX * 64;

    k1_range_proj<<<NBLK, 256, 0, stream>>>(
        semantic, rp_w1, rp_b1, rp_g, rp_be, rp_w2, rp_b2, px_t, sqnorm);
    k23_fused<<<NBLK, 256, 0, stream>>>(
        px_t, sqnorm, semantic, spatial,
        fx_w1, fx_b1, fx_g, fx_be, fx_w2, fx_b2,
        op_w1, op_b1, op_g, op_be, op_w2, op_b2,
        sigma, (float*)d_out);
}

// Round 5
// 201.239 us; speedup vs baseline: 2.9773x; 1.3646x over previous
//
#include <hip/hip_runtime.h>

constexpr int B = 2, C = 64, H = 112, W = 112;
constexpr int HW = H * W;          // 12544
constexpr int NPIX = B * HW;       // 25088
constexpr int TILES_X = 14;
constexpr int TILES_PER_IMG = 196;
constexpr int NBLK = B * TILES_PER_IMG;   // 392
constexpr float EPS_LN = 1e-6f, EPS_NORM = 1e-7f;

__device__ __forceinline__ float rcp_fast(float x) { return __builtin_amdgcn_rcpf(x); }
__device__ __forceinline__ float sigmoid_f(float x) { return rcp_fast(1.f + __expf(-x)); }
// Force wave-uniformity so the compiler emits s_load for weight rows.
__device__ __forceinline__ int uni(int x) { return __builtin_amdgcn_readfirstlane(x); }

// ---------------------------------------------------------------------------
// k1: px = range_proj(semantic). 256 threads / 8x8 tile; 4 waves split the 64
// output channels (16 each). lane = pixel. Weights via scalar loads (uniform o).
// ---------------------------------------------------------------------------
__global__ __launch_bounds__(256) void k1_range_proj(
    const float* __restrict__ sem,
    const float* __restrict__ w1, const float* __restrict__ b1,
    const float* __restrict__ g,  const float* __restrict__ be,
    const float* __restrict__ w2, const float* __restrict__ b2,
    float* __restrict__ px_t, float* __restrict__ sqnorm)
{
    __shared__ float f_scr[64 * 64];    // [o][pix]
    __shared__ float px_scr[64 * 65];   // [o][pix] pitch 65 (transpose-out)
    __shared__ float pm[4 * 64], ps[4 * 64], p2[4 * 64];

    const int tid = threadIdx.x, lane = tid & 63, wv = tid >> 6;
    const int blk = blockIdx.x, b = blk / TILES_PER_IMG, t = blk - b * TILES_PER_IMG;
    const int ty = t / TILES_X, tx = t - ty * TILES_X;
    const int h = ty * 8 + (lane >> 3), w = tx * 8 + (lane & 7);
    const int hw = h * W + w;

    float sv[64];
#pragma unroll
    for (int k = 0; k < 64; ++k) sv[k] = sem[(size_t)(b * 64 + k) * HW + hw];

    const int o0 = uni(wv * 16);
    float macc = 0.f, sacc = 0.f;
    for (int j = 0; j < 16; ++j) {
        const int o = o0 + j;                 // uniform
        const float* wr = &w1[o * 64];
        float a0 = 0, a1 = 0, a2 = 0, a3 = 0;
#pragma unroll
        for (int k = 0; k < 64; k += 4) {
            a0 += wr[k] * sv[k];       a1 += wr[k + 1] * sv[k + 1];
            a2 += wr[k + 2] * sv[k + 2]; a3 += wr[k + 3] * sv[k + 3];
        }
        float f = (a0 + a1) + (a2 + a3) + b1[o];
        f_scr[o * 64 + lane] = f;      // bank=lane%32: 2-way, free
        macc += f; sacc += f * f;
    }
    pm[wv * 64 + lane] = macc; ps[wv * 64 + lane] = sacc;
    __syncthreads();
    float m  = (pm[lane] + pm[64 + lane] + pm[128 + lane] + pm[192 + lane]) * (1.f / 64.f);
    float va = (ps[lane] + ps[64 + lane] + ps[128 + lane] + ps[192 + lane]) * (1.f / 64.f) - m * m;
    float rstd = rsqrtf(va + EPS_LN);

    float s[64];
#pragma unroll
    for (int k = 0; k < 64; ++k) {
        float y = g[k] * (f_scr[k * 64 + lane] - m) * rstd + be[k];
        s[k] = y * sigmoid_f(y);
    }
    float sq = 0.f;
    for (int j = 0; j < 16; ++j) {
        const int o = o0 + j;                 // uniform
        const float* wr = &w2[o * 64];
        float a0 = 0, a1 = 0, a2 = 0, a3 = 0;
#pragma unroll
        for (int k = 0; k < 64; k += 4) {
            a0 += wr[k] * s[k];        a1 += wr[k + 1] * s[k + 1];
            a2 += wr[k + 2] * s[k + 2]; a3 += wr[k + 3] * s[k + 3];
        }
        float z = (a0 + a1) + (a2 + a3) + b2[o];
        px_scr[o * 65 + lane] = z;     // bank=(o+lane)%32: conflict-free
        sq += z * z;
    }
    p2[wv * 64 + lane] = sq;
    __syncthreads();
    if (wv == 0)
        sqnorm[(size_t)b * HW + hw] = p2[lane] + p2[64 + lane] + p2[128 + lane] + p2[192 + lane];
    // transpose-out: wave wv stores pixels o0..o0+15; lane = channel
    for (int j = 0; j < 16; ++j) {
        int ii = o0 + j;
        int hwi = (ty * 8 + (ii >> 3)) * W + tx * 8 + (ii & 7);
        px_t[((size_t)b * HW + hwi) * 64 + lane] = px_scr[lane * 65 + ii];  // (lane+ii)%32: cf
    }
}

// ---------------------------------------------------------------------------
// k23: fused bilateral weights + gated fixup + normalize + neighborhood
// reduction + output_proj. 256 threads / 8x8 tile. Weights via scalar loads.
// Halo layout: element (r, c) at (r<<6) | (c ^ ((r&7)<<2)) -> b128 accesses at
// the 1KB/128B LDS floor.
// ---------------------------------------------------------------------------
__global__ __launch_bounds__(256) void k23_fused(
    const float* __restrict__ px_t, const float* __restrict__ sqnorm,
    const float* __restrict__ sem,  const float* __restrict__ spat,
    const float* __restrict__ fw1, const float* __restrict__ fb1,
    const float* __restrict__ fg,  const float* __restrict__ fbe,
    const float* __restrict__ fw2, const float* __restrict__ fb2,
    const float* __restrict__ w1, const float* __restrict__ b1,
    const float* __restrict__ g,  const float* __restrict__ be,
    const float* __restrict__ w2, const float* __restrict__ b2,
    const float* __restrict__ sigma_, float* __restrict__ out)
{
    __shared__ __align__(16) float halo[196 * 64];      // 50176 B (aliased below)
    __shared__ __align__(16) float comb_scr[49 * 64];   // 12544 B
    __shared__ float sqn_l[196];
    __shared__ float pm[4 * 64], ps[4 * 64], pt[4 * 64];

    const int tid = threadIdx.x, lane = tid & 63, wv = tid >> 6;
    const int blk = blockIdx.x, b = blk / TILES_PER_IMG, t = blk - b * TILES_PER_IMG;
    const int ty = t / TILES_X, tx = t - ty * TILES_X;
    const int h = ty * 8 + (lane >> 3), w = tx * 8 + (lane & 7);
    const int hw = h * W + w;
    const int h0 = ty * 8 - 3, w0 = tx * 8 - 3;

    // ---- phase 1: stage px halo (pixel-major source: coalesced, cf writes) ----
    for (int i = 0; i < 49; ++i) {
        int idx = i * 256 + tid; int r = idx >> 6, c = idx & 63;
        int ry = (r * 2341) >> 15, rx = r - ry * 14;     // exact /14 for r<256
        int hh = h0 + ry, ww = w0 + rx;
        bool valid = (unsigned)hh < (unsigned)H && (unsigned)ww < (unsigned)W;
        float v = 0.f;
        if (valid) v = px_t[((size_t)b * HW + hh * W + ww) * 64 + c];
        halo[(r << 6) | (c ^ ((r & 7) << 2))] = v;
    }
    if (tid < 196) {
        int ry = (tid * 2341) >> 15, rx = tid - ry * 14;
        int hh = h0 + ry, ww = w0 + rx;
        bool valid = (unsigned)hh < (unsigned)H && (unsigned)ww < (unsigned)W;
        float v = 0.f;
        if (valid) v = sqnorm[(size_t)b * HW + hh * W + ww];
        sqn_l[tid] = v;
    }
    __syncthreads();

    // ---- phase 2: bilateral weights, neighbors split across waves ----
    const int rbase = (lane >> 3) * 14 + (lane & 7);
    const int rp = rbase + 45;
    const int ctr = (rp << 6) ^ ((rp & 7) << 2);
    float cv[64];
#pragma unroll
    for (int q = 0; q < 16; ++q) {
        float4 v = *(const float4*)&halo[ctr ^ (q << 2)];
        cv[4 * q] = v.x; cv[4 * q + 1] = v.y; cv[4 * q + 2] = v.z; cv[4 * q + 3] = v.w;
    }
    const float sqc = sqn_l[rp];
    const float sg_ = sigma_[0];
    const float inv2s2 = rcp_fast(2.f * sg_ * sg_);
    for (int i = 0; i < 13; ++i) {
        int n = uni(wv + 4 * i);
        if (n < 49) {
            int ryn = n / 7, rxn = n - ryn * 7;
            int dy = ryn - 3, dx = rxn - 3;
            int rn = rbase + ryn * 14 + rxn;
            int bx = (rn << 6) ^ ((rn & 7) << 2);
            float d0 = 0, d1 = 0, d2 = 0, d3 = 0;
#pragma unroll
            for (int q = 0; q < 16; ++q) {
                float4 v = *(const float4*)&halo[bx ^ (q << 2)];
                d0 += v.x * cv[4 * q];     d1 += v.y * cv[4 * q + 1];
                d2 += v.z * cv[4 * q + 2]; d3 += v.w * cv[4 * q + 3];
            }
            float dot = (d0 + d1) + (d2 + d3);
            float dist2 = fmaxf(sqn_l[rn] + sqc - 2.f * dot, 0.f);
            bool valid = (unsigned)(h + dy) < (unsigned)H && (unsigned)(w + dx) < (unsigned)W;
            float d2n = (float)(dy * dy + dx * dx);
            comb_scr[n * 64 + lane] = valid ? __expf(-(dist2 * (1.f / 128.f) + d2n * inv2s2)) : 0.f;
        }
    }
    __syncthreads();

    // ---- phase 3: gated fixup, outputs split across waves ----
    float cb[49];
#pragma unroll
    for (int n = 0; n < 49; ++n) cb[n] = comb_scr[n * 64 + lane];
    float svv[64];
#pragma unroll
    for (int k = 0; k < 64; ++k) svv[k] = sem[(size_t)(b * 64 + k) * HW + hw];
    float* f_scr = halo;                 // px halo dead after phase 2
    float macc = 0.f, sacc = 0.f;
    for (int i = 0; i < 13; ++i) {
        const int o = uni(wv + 4 * i);   // uniform -> s_load weight row
        if (o < 49) {
            const float* wr = &fw1[o * 113];
            float a0 = 0, a1 = 0, a2 = 0, a3 = 0;
#pragma unroll
            for (int k = 0; k < 48; k += 4) {
                a0 += wr[k] * cb[k];       a1 += wr[k + 1] * cb[k + 1];
                a2 += wr[k + 2] * cb[k + 2]; a3 += wr[k + 3] * cb[k + 3];
            }
            a0 += wr[48] * cb[48];
            const float* wr2 = wr + 49;
#pragma unroll
            for (int k = 0; k < 64; k += 4) {
                a0 += wr2[k] * svv[k];       a1 += wr2[k + 1] * svv[k + 1];
                a2 += wr2[k + 2] * svv[k + 2]; a3 += wr2[k + 3] * svv[k + 3];
            }
            float f = (a0 + a1) + (a2 + a3) + fb1[o];
            f_scr[o * 64 + lane] = f;
            macc += f; sacc += f * f;
        }
    }
    pm[wv * 64 + lane] = macc; ps[wv * 64 + lane] = sacc;
    __syncthreads();
    {
        float m  = (pm[lane] + pm[64 + lane] + pm[128 + lane] + pm[192 + lane]) * (1.f / 49.f);
        float va = (ps[lane] + ps[64 + lane] + ps[128 + lane] + ps[192 + lane]) * (1.f / 49.f) - m * m;
        float rstd = rsqrtf(va + EPS_LN);
        float s[49];
#pragma unroll
        for (int k = 0; k < 49; ++k) {
            float y = fg[k] * (f_scr[k * 64 + lane] - m) * rstd + fbe[k];
            s[k] = y * sigmoid_f(y);
        }
        float tacc = 0.f;
        for (int i = 0; i < 13; ++i) {
            const int o = uni(wv + 4 * i);
            if (o < 49) {
                const float* wr = &fw2[o * 49];
                float a0 = 0, a1 = 0, a2 = 0, a3 = 0;
#pragma unroll
                for (int k = 0; k < 48; k += 4) {
                    a0 += wr[k] * s[k];       a1 += wr[k + 1] * s[k + 1];
                    a2 += wr[k + 2] * s[k + 2]; a3 += wr[k + 3] * s[k + 3];
                }
                a0 += wr[48] * s[48];
                float fo = (a0 + a1) + (a2 + a3) + fb2[o];
                float gate = 1.f + sigmoid_f(fo);
                float cx = comb_scr[o * 64 + lane] * gate;
                comb_scr[o * 64 + lane] = cx;
                tacc += cx;
            }
        }
        pt[wv * 64 + lane] = tacc;
    }
    __syncthreads();   // all f_scr reads done -> halo restage is safe
    const float inv = rcp_fast(pt[lane] + pt[64 + lane] + pt[128 + lane] + pt[192 + lane] + EPS_NORM);

    // ---- phase 4: restage halo with spatial (channel-major source) ----
    for (int i = 0; i < 13; ++i) {
        int idx = i * 256 + tid;          // idx = cq*196 + r
        if (idx < 3136) {
            int cq = idx / 196, r = idx - cq * 196;
            int ry = (r * 2341) >> 15, rx = r - ry * 14;
            int hh = h0 + ry, ww = w0 + rx;
            bool valid = (unsigned)hh < (unsigned)H && (unsigned)ww < (unsigned)W;
            float4 v = make_float4(0.f, 0.f, 0.f, 0.f);
            if (valid) {
                const float* sp = &spat[(size_t)(b * 64 + cq * 4) * HW + hh * W + ww];
                v.x = sp[0]; v.y = sp[HW]; v.z = sp[2 * HW]; v.w = sp[3 * HW];
            }
            *(float4*)&halo[(r << 6) | ((cq ^ (r & 7)) << 2)] = v;
        }
    }
    __syncthreads();

    // ---- phase 5: weighted neighborhood reduction, channels split across waves ----
    const int c0 = uni(wv * 16);
    float acc[16];
#pragma unroll
    for (int j = 0; j < 16; ++j) acc[j] = 0.f;
    for (int n = 0; n < 49; ++n) {
        int ryn = n / 7, rxn = n - ryn * 7;
        int rn = rbase + ryn * 14 + rxn;
        int bx = (rn << 6) ^ ((rn & 7) << 2);
        float cn = comb_scr[n * 64 + lane] * inv;
#pragma unroll
        for (int q = 0; q < 4; ++q) {
            float4 v = *(const float4*)&halo[bx ^ (((c0 >> 2) + q) << 2)];
            acc[4 * q]     += cn * v.x; acc[4 * q + 1] += cn * v.y;
            acc[4 * q + 2] += cn * v.z; acc[4 * q + 3] += cn * v.w;
        }
    }
    __syncthreads();   // halo reads done -> av/f2 aliases safe

    // ---- phase 6: output_proj ----
    float* av = halo;                 // [c][pix] 64x64
    float* f2 = halo + 4096;          // [o][pix] 64x64
    for (int j = 0; j < 16; ++j) av[(c0 + j) * 64 + lane] = acc[j];
    __syncthreads();
    float xv[64];
#pragma unroll
    for (int k = 0; k < 64; ++k) xv[k] = av[k * 64 + lane];
    float macc2 = 0.f, sacc2 = 0.f;
    for (int j = 0; j < 16; ++j) {
        const int o = c0 + j;             // uniform
        const float* wr = &w1[o * 64];
        float a0 = 0, a1 = 0, a2 = 0, a3 = 0;
#pragma unroll
        for (int k = 0; k < 64; k += 4) {
            a0 += wr[k] * xv[k];       a1 += wr[k + 1] * xv[k + 1];
            a2 += wr[k + 2] * xv[k + 2]; a3 += wr[k + 3] * xv[k + 3];
        }
        float f = (a0 + a1) + (a2 + a3) + b1[o];
        f2[o * 64 + lane] = f;
        macc2 += f; sacc2 += f * f;
    }
    pm[wv * 64 + lane] = macc2; ps[wv * 64 + lane] = sacc2;
    __syncthreads();
    float m  = (pm[lane] + pm[64 + lane] + pm[128 + lane] + pm[192 + lane]) * (1.f / 64.f);
    float va = (ps[lane] + ps[64 + lane] + ps[128 + lane] + ps[192 + lane]) * (1.f / 64.f) - m * m;
    float rstd = rsqrtf(va + EPS_LN);
    float yv[64];
#pragma unroll
    for (int k = 0; k < 64; ++k)
        yv[k] = g[k] * (f2[k * 64 + lane] - m) * rstd + be[k];
    for (int j = 0; j < 16; ++j) {
        const int o = c0 + j;             // uniform
        const float* wr = &w2[o * 64];
        float a0 = 0, a1 = 0, a2 = 0, a3 = 0;
#pragma unroll
        for (int k = 0; k < 64; k += 4) {
            a0 += wr[k] * yv[k];       a1 += wr[k + 1] * yv[k + 1];
            a2 += wr[k + 2] * yv[k + 2]; a3 += wr[k + 3] * yv[k + 3];
        }
        float z = (a0 + a1) + (a2 + a3) + b2[o];
        out[(size_t)(b * 64 + o) * HW + hw] = z;
    }
}

extern "C" void kernel_launch(void* const* d_in, const int* in_sizes, int n_in,
                              void* d_out, int out_size, void* d_ws, size_t ws_size,
                              hipStream_t stream)
{
    const float* spatial  = (const float*)d_in[0];
    const float* semantic = (const float*)d_in[1];
    const float* rp_w1 = (const float*)d_in[2];
    const float* rp_b1 = (const float*)d_in[3];
    const float* rp_g  = (const float*)d_in[4];
    const float* rp_be = (const float*)d_in[5];
    const float* rp_w2 = (const float*)d_in[6];
    const float* rp_b2 = (const float*)d_in[7];
    const float* fx_w1 = (const float*)d_in[8];
    const float* fx_b1 = (const float*)d_in[9];
    const float* fx_g  = (const float*)d_in[10];
    const float* fx_be = (const float*)d_in[11];
    const float* fx_w2 = (const float*)d_in[12];
    const float* fx_b2 = (const float*)d_in[13];
    const float* op_w1 = (const float*)d_in[14];
    const float* op_b1 = (const float*)d_in[15];
    const float* op_g  = (const float*)d_in[16];
    const float* op_be = (const float*)d_in[17];
    const float* op_w2 = (const float*)d_in[18];
    const float* op_b2 = (const float*)d_in[19];
    const float* sigma = (const float*)d_in[20];

    float* ws = (float*)d_ws;
    float* px_t   = ws;
    float* sqnorm = px_t + (size_t)NPIX * 64;

    k1_range_proj<<<NBLK, 256, 0, stream>>>(
        semantic, rp_w1, rp_b1, rp_g, rp_be, rp_w2, rp_b2, px_t, sqnorm);
    k23_fused<<<NBLK, 256, 0, stream>>>(
        px_t, sqnorm, semantic, spatial,
        fx_w1, fx_b1, fx_g, fx_be, fx_w2, fx_b2,
        op_w1, op_b1, op_g, op_be, op_w2, op_b2,
        sigma, (float*)d_out);
}